// Round 4
// baseline (1285.521 us; speedup 1.0000x reference)
//
#include <hip/hip_runtime.h>
#include <math.h>

#define TLEN 1024
#define BSZ  16
#define DIN  128
#define KP   16
#define NEIG 64
#define MOUT 128
#define CHUNK_T 256
#define NCHUNK  4

// ws layout (float units) — everything f32 now (complex64-faithful pipeline)
static constexpr size_t XCQ_OFF = 0;        // 262144: xc quantized f32 [t][b][k]
static constexpr size_t LAM_OFF = 262144;   // 2048:  lambda c32 [k*64+j] float2
static constexpr size_t BQ_OFF  = 264192;   // 2048:  B' c32 [k*64+j] float2
static constexpr size_t CP_OFF  = 266240;   // 262144: Cp c32 [(k*64+j)*128+m] float2
static constexpr size_t ST_OFF  = 528384;   // 65536: scan state (s1,s2) c32 per mode-lane
static constexpr size_t S2_OFF  = 593920;   // 8388608: s2 chunk, 4096 rows x 1024 modes float2
// total: 8,982,528 floats = 35.9 MB (ws proven >= 69.7 MB earlier)

__device__ __forceinline__ float f32cos(float x) { return (float)cos((double)x); }
__device__ __forceinline__ float f32sin(float x) { return (float)sin((double)x); }

// numpy complex64 division (Smith's algorithm, loops.c.src), all ops f32-rounded.
__device__ __forceinline__ float2 cdiv32(float ar, float ai, float cr, float ci) {
  float2 o;
  if (fabsf(ci) <= fabsf(cr)) {
    float rat = __fdiv_rn(ci, cr);
    float scl = __fdiv_rn(1.0f, __fadd_rn(cr, __fmul_rn(ci, rat)));
    o.x = __fmul_rn(__fadd_rn(ar, __fmul_rn(ai, rat)), scl);
    o.y = __fmul_rn(__fsub_rn(ai, __fmul_rn(ar, rat)), scl);
  } else {
    float rat = __fdiv_rn(cr, ci);
    float scl = __fdiv_rn(1.0f, __fadd_rn(ci, __fmul_rn(cr, rat)));
    o.x = __fmul_rn(__fadd_rn(__fmul_rn(ar, rat), ai), scl);
    o.y = __fmul_rn(__fsub_rn(__fmul_rn(ai, rat), ar), scl);
  }
  return o;
}

// ---------------------------------------------------------------------------
// lambda_q[k,j] = c32(exp(i*th_j)) and B'_q[k,j] = c32 exp(-sum_i clog32(1 - lam_i/lam_j))
// sum ascending i (numpy axis=1 reduction order), full 64-spectrum, c32-faithful.
__global__ void k_lam_B(const float* __restrict__ theta, float2* __restrict__ lam,
                        float2* __restrict__ Bq) {
  int idx = blockIdx.x * blockDim.x + threadIdx.x;
  if (idx >= KP * NEIG) return;
  int k = idx >> 6, j = idx & 63;
  float thj = (j < 32) ? theta[k * 32 + j] : -theta[k * 32 + (j - 32)];
  float ljr = f32cos(thj), lji = f32sin(thj);
  lam[idx] = make_float2(ljr, lji);
  float sr = 0.f, si = 0.f;
  for (int i = 0; i < NEIG; ++i) {
    if (i == j) continue;                    // diag: log(1-0)=0 exactly
    float thi = (i < 32) ? theta[k * 32 + i] : -theta[k * 32 + (i - 32)];
    float lir = f32cos(thi), lii = f32sin(thi);
    float2 r = cdiv32(lir, lii, ljr, lji);   // lam_i / lam_j  (c32 Smith)
    float tr = __fsub_rn(1.0f, r.x);
    float ti = __fsub_rn(0.0f, r.y);
    // clogf(t) = (logf(hypotf), atan2f) — compute in f64, round to f32 (~CR)
    double h = sqrt((double)tr * tr + (double)ti * ti);
    float lre = (float)log(h);
    float lim = (float)atan2((double)ti, (double)tr);
    sr = __fadd_rn(sr, lre);                 // sequential ascending i (c32)
    si = __fadd_rn(si, lim);
  }
  // B = cexp(-S): expf(-sr) * (cosf(-si), sinf(-si)), f32 mults
  float er = (float)exp((double)(-sr));
  float cc = f32cos(-si), ss = f32sin(-si);
  Bq[idx] = make_float2(__fmul_rn(er, cc), __fmul_rn(er, ss));
}

// ---------------------------------------------------------------------------
// Cp[k,j,m] = c32 sum_i (ascending) C[k,m,i] * exp(i * (-f32((63-i)*th_j)))
// The f32 rounding of p*theta (range ~200 rad) is a dominant deterministic
// error in the reference — reproduced exactly here.
__global__ void k_Cp(const float* __restrict__ theta, const float* __restrict__ C,
                     float2* __restrict__ Cp) {
  int idx = blockIdx.x * blockDim.x + threadIdx.x;
  if (idx >= KP * NEIG * MOUT) return;
  int m = idx & 127;
  int kj = idx >> 7;
  int j = kj & 63, k = kj >> 6;
  float lnim = (j < 32) ? theta[k * 32 + j] : -theta[k * 32 + (j - 32)];
  const float* Crow = C + ((size_t)k * MOUT + m) * NEIG;
  float ar = 0.f, ai = 0.f;
  for (int i = 0; i < NEIG; ++i) {
    float p = (float)(63 - i);
    float ph = -__fmul_rn(p, lnim);          // c32 mult rounding, then exact negate
    float Ur = f32cos(ph), Ui = f32sin(ph);
    float Cv = Crow[i];
    ar = __fadd_rn(ar, __fmul_rn(Cv, Ur));   // C real: b=0 terms vanish exactly
    ai = __fadd_rn(ai, __fmul_rn(Cv, Ui));
  }
  Cp[(size_t)(k * 64 + j) * MOUT + m] = make_float2(ar, ai);
}

// ---------------------------------------------------------------------------
// xc[t,b,k] = f32( f64 sum_d x[b,t,d]*R[d,k] )  — center-of-distribution vs BLAS
__global__ void k_xc(const float* __restrict__ x, const float* __restrict__ R,
                     float* __restrict__ xcq) {
  int idx = blockIdx.x * blockDim.x + threadIdx.x;
  if (idx >= TLEN * BSZ * KP) return;
  int k = idx & 15;
  int b = (idx >> 4) & 15;
  int t = idx >> 8;
  const float4* xr = (const float4*)(x + ((size_t)b * TLEN + t) * DIN);
  double acc = 0.0;
  #pragma unroll 8
  for (int d4 = 0; d4 < DIN / 4; ++d4) {
    float4 v = xr[d4];
    acc = fma((double)v.x, (double)R[(d4 * 4 + 0) * KP + k], acc);
    acc = fma((double)v.y, (double)R[(d4 * 4 + 1) * KP + k], acc);
    acc = fma((double)v.z, (double)R[(d4 * 4 + 2) * KP + k], acc);
    acc = fma((double)v.w, (double)R[(d4 * 4 + 3) * KP + k], acc);
  }
  xcq[idx] = (float)acc;
}

// ---------------------------------------------------------------------------
// Fused two-pass scan, complex64-faithful (every mul/add separately f32-rounded).
// Full 64-mode spectrum; lane j = mode j. Chunked over T (state carried in ws).
__global__ __launch_bounds__(64) void k_scan(const float2* __restrict__ lam,
                        const float2* __restrict__ Bq,
                        const float* __restrict__ xcq,
                        float2* __restrict__ S2,
                        float* __restrict__ state, int c) {
  int j = threadIdx.x;                 // 0..63
  int chain = blockIdx.x;              // b*16 + k
  int b = chain >> 4, k = chain & 15;
  int mode = k * 64 + j;
  float lr = lam[mode].x, li = lam[mode].y;
  float Br = Bq[mode].x,  Bi = Bq[mode].y;
  float* st = state + (size_t)(chain * 64 + j) * 4;
  float s1r, s1i, s2r, s2i;
  if (c == 0) { s1r = s1i = s2r = s2i = 0.f; }
  else        { s1r = st[0]; s1i = st[1]; s2r = st[2]; s2i = st[3]; }
  int t0 = c * CHUNK_T;
  for (int tl = 0; tl < CHUNK_T; ++tl) {
    int t = t0 + tl;
    if (t > 0) {
      float xq  = xcq[(size_t)(t - 1) * (BSZ * KP) + b * KP + k];
      float bxr = __fmul_rn(xq, Br), bxi = __fmul_rn(xq, Bi);   // Bx (xc real)
      // ls = lam * s1[t-1]  (c32 naive cmul)
      float lsr = __fsub_rn(__fmul_rn(lr, s1r), __fmul_rn(li, s1i));
      float lsi = __fadd_rn(__fmul_rn(lr, s1i), __fmul_rn(li, s1r));
      // alpha = f32( 1 / sqrt(1 + hypot(ls)^2) )
      float h  = (float)sqrt((double)lsr * lsr + (double)lsi * lsi);
      float h2 = __fmul_rn(h, h);
      float sm = __fadd_rn(1.0f, h2);
      float al = __fdiv_rn(1.0f, __fsqrt_rn(sm));
      // a2 = alpha * lam  (alpha real)
      float a2r = __fmul_rn(al, lr), a2i = __fmul_rn(al, li);
      // s2 = a2*s2 + bx
      float t2r = __fsub_rn(__fmul_rn(a2r, s2r), __fmul_rn(a2i, s2i));
      float t2i = __fadd_rn(__fmul_rn(a2r, s2i), __fmul_rn(a2i, s2r));
      s2r = __fadd_rn(t2r, bxr);
      s2i = __fadd_rn(t2i, bxi);
      // s1 = ls + bx
      s1r = __fadd_rn(lsr, bxr);
      s1i = __fadd_rn(lsi, bxi);
    }
    S2[(size_t)(tl * BSZ + b) * 1024 + mode] = make_float2(s2r, s2i);
  }
  st[0] = s1r; st[1] = s1i; st[2] = s2r; st[3] = s2i;
}

// ---------------------------------------------------------------------------
// y: per (row=(t,b), m): for k ascending: acc_n = c32 seq sum over n of
// Re(s2*Cp); y_k = (acc_n + f32(xc*D)) + Do; msum += y_k; out = msum/16.
__global__ __launch_bounds__(256) void k_y(const float2* __restrict__ S2,
                     const float2* __restrict__ Cp, const float* __restrict__ xcq,
                     const float* __restrict__ D, const float* __restrict__ Dov,
                     float* __restrict__ out, int c) {
  __shared__ float2 sCp[64][128];   // 64 KB
  __shared__ float2 sS2[16][64];    // 8 KB
  __shared__ float  sD[16][128];    // 8 KB
  __shared__ float  sDo[128];
  __shared__ float  sXc[16][16];
  int tid = threadIdx.x;
  int rowBase = blockIdx.x * 16;    // chunk-local row
  for (int i = tid; i < KP * MOUT; i += 256) sD[i >> 7][i & 127] = D[i];
  if (tid < 128) sDo[tid] = Dov[tid];
  { int r = tid >> 4, kk = tid & 15;
    sXc[r][kk] = xcq[(size_t)(c * 4096 + rowBase + r) * KP + kk]; }
  int r0 = (tid >> 5) * 2;          // 2 rows per thread
  int c0 = (tid & 31) * 4;          // 4 cols per thread
  float msum[2][4] = {};
  for (int k = 0; k < KP; ++k) {
    __syncthreads();                // protects tiles from prev iter + initial loads
    for (int i = tid; i < 64 * 128; i += 256) { int n = i >> 7, m = i & 127;
      sCp[n][m] = Cp[(size_t)(k * 64 + n) * MOUT + m]; }
    for (int i = tid; i < 16 * 64; i += 256) { int r = i >> 6, n = i & 63;
      sS2[r][n] = S2[(size_t)(rowBase + r) * 1024 + k * 64 + n]; }
    __syncthreads();
    float accn[2][4] = {};
    for (int n = 0; n < 64; ++n) {
      float2 cpv[4];
      #pragma unroll
      for (int cc = 0; cc < 4; ++cc) cpv[cc] = sCp[n][c0 + cc];
      #pragma unroll
      for (int rr = 0; rr < 2; ++rr) {
        float2 s = sS2[r0 + rr][n];
        #pragma unroll
        for (int cc = 0; cc < 4; ++cc) {
          float term = __fsub_rn(__fmul_rn(s.x, cpv[cc].x), __fmul_rn(s.y, cpv[cc].y));
          accn[rr][cc] = __fadd_rn(accn[rr][cc], term);
        }
      }
    }
    #pragma unroll
    for (int rr = 0; rr < 2; ++rr)
      #pragma unroll
      for (int cc = 0; cc < 4; ++cc) {
        float yk = __fadd_rn(accn[rr][cc], __fmul_rn(sXc[r0 + rr][k], sD[k][c0 + cc]));
        yk = __fadd_rn(yk, sDo[c0 + cc]);
        msum[rr][cc] = __fadd_rn(msum[rr][cc], yk);   // mean: ascending k
      }
  }
  #pragma unroll
  for (int rr = 0; rr < 2; ++rr) {
    int rg = c * 4096 + rowBase + r0 + rr;
    int t = rg >> 4, b = rg & 15;
    float* op = out + ((size_t)b * TLEN + t) * MOUT + c0;
    #pragma unroll
    for (int cc = 0; cc < 4; ++cc) op[cc] = __fdiv_rn(msum[rr][cc], 16.0f);
  }
}

// ---------------------------------------------------------------------------
extern "C" void kernel_launch(void* const* d_in, const int* in_sizes, int n_in,
                              void* d_out, int out_size, void* d_ws, size_t ws_size,
                              hipStream_t stream) {
  const float* x     = (const float*)d_in[0];
  const float* R     = (const float*)d_in[1];
  const float* theta = (const float*)d_in[2];
  const float* C     = (const float*)d_in[3];
  const float* D     = (const float*)d_in[4];
  const float* Do    = (const float*)d_in[5];
  float* out = (float*)d_out;
  float* ws  = (float*)d_ws;
  float*  xcq = ws + XCQ_OFF;
  float2* lam = (float2*)(ws + LAM_OFF);
  float2* Bq  = (float2*)(ws + BQ_OFF);
  float2* Cp  = (float2*)(ws + CP_OFF);
  float*  st  = ws + ST_OFF;
  float2* S2  = (float2*)(ws + S2_OFF);

  hipLaunchKernelGGL(k_lam_B, dim3(4),    dim3(256), 0, stream, theta, lam, Bq);
  hipLaunchKernelGGL(k_Cp,    dim3(512),  dim3(256), 0, stream, theta, C, Cp);
  hipLaunchKernelGGL(k_xc,    dim3(1024), dim3(256), 0, stream, x, R, xcq);
  for (int c = 0; c < NCHUNK; ++c) {
    hipLaunchKernelGGL(k_scan, dim3(256), dim3(64),  0, stream, lam, Bq, xcq, S2, st, c);
    hipLaunchKernelGGL(k_y,    dim3(256), dim3(256), 0, stream, S2, Cp, xcq, D, Do, out, c);
  }
}

// Round 5
// 726.098 us; speedup vs baseline: 1.7705x; 1.7705x over previous
//
#include <hip/hip_runtime.h>
#include <math.h>

#define TLEN 1024
#define BSZ  16
#define DIN  128
#define KP   16
#define NEIG 64
#define MOUT 128
#define CHUNK_T 256
#define NCHUNK  4

// ws layout (float units) — complex64-faithful pipeline (unchanged from round 4)
static constexpr size_t XCQ_OFF = 0;        // 262144: xc quantized f32 [t][b][k]
static constexpr size_t LAM_OFF = 262144;   // 2048:  lambda c32 [k*64+j] float2
static constexpr size_t BQ_OFF  = 264192;   // 2048:  B' c32 [k*64+j] float2
static constexpr size_t CP_OFF  = 266240;   // 262144: Cp c32 [(k*64+j)*128+m] float2
static constexpr size_t ST_OFF  = 528384;   // 65536: scan state (s1,s2) c32 per mode-lane
static constexpr size_t S2_OFF  = 593920;   // 8388608: s2 chunk, 4096 rows x 1024 modes float2
// total: 8,982,528 floats = 35.9 MB

__device__ __forceinline__ float f32cos(float x) { return (float)cos((double)x); }
__device__ __forceinline__ float f32sin(float x) { return (float)sin((double)x); }

// numpy complex64 division (Smith's algorithm), all ops f32-rounded.
__device__ __forceinline__ float2 cdiv32(float ar, float ai, float cr, float ci) {
  float2 o;
  if (fabsf(ci) <= fabsf(cr)) {
    float rat = __fdiv_rn(ci, cr);
    float scl = __fdiv_rn(1.0f, __fadd_rn(cr, __fmul_rn(ci, rat)));
    o.x = __fmul_rn(__fadd_rn(ar, __fmul_rn(ai, rat)), scl);
    o.y = __fmul_rn(__fsub_rn(ai, __fmul_rn(ar, rat)), scl);
  } else {
    float rat = __fdiv_rn(cr, ci);
    float scl = __fdiv_rn(1.0f, __fadd_rn(ci, __fmul_rn(cr, rat)));
    o.x = __fmul_rn(__fadd_rn(__fmul_rn(ar, rat), ai), scl);
    o.y = __fmul_rn(__fsub_rn(__fmul_rn(ai, rat), ar), scl);
  }
  return o;
}

// ---------------------------------------------------------------------------
__global__ void k_lam_B(const float* __restrict__ theta, float2* __restrict__ lam,
                        float2* __restrict__ Bq) {
  int idx = blockIdx.x * blockDim.x + threadIdx.x;
  if (idx >= KP * NEIG) return;
  int k = idx >> 6, j = idx & 63;
  float thj = (j < 32) ? theta[k * 32 + j] : -theta[k * 32 + (j - 32)];
  float ljr = f32cos(thj), lji = f32sin(thj);
  lam[idx] = make_float2(ljr, lji);
  float sr = 0.f, si = 0.f;
  for (int i = 0; i < NEIG; ++i) {
    if (i == j) continue;
    float thi = (i < 32) ? theta[k * 32 + i] : -theta[k * 32 + (i - 32)];
    float lir = f32cos(thi), lii = f32sin(thi);
    float2 r = cdiv32(lir, lii, ljr, lji);
    float tr = __fsub_rn(1.0f, r.x);
    float ti = __fsub_rn(0.0f, r.y);
    double h = sqrt((double)tr * tr + (double)ti * ti);
    float lre = (float)log(h);
    float lim = (float)atan2((double)ti, (double)tr);
    sr = __fadd_rn(sr, lre);
    si = __fadd_rn(si, lim);
  }
  float er = (float)exp((double)(-sr));
  float cc = f32cos(-si), ss = f32sin(-si);
  Bq[idx] = make_float2(__fmul_rn(er, cc), __fmul_rn(er, ss));
}

// ---------------------------------------------------------------------------
__global__ void k_Cp(const float* __restrict__ theta, const float* __restrict__ C,
                     float2* __restrict__ Cp) {
  int idx = blockIdx.x * blockDim.x + threadIdx.x;
  if (idx >= KP * NEIG * MOUT) return;
  int m = idx & 127;
  int kj = idx >> 7;
  int j = kj & 63, k = kj >> 6;
  float lnim = (j < 32) ? theta[k * 32 + j] : -theta[k * 32 + (j - 32)];
  const float* Crow = C + ((size_t)k * MOUT + m) * NEIG;
  float ar = 0.f, ai = 0.f;
  for (int i = 0; i < NEIG; ++i) {
    float p = (float)(63 - i);
    float ph = -__fmul_rn(p, lnim);
    float Ur = f32cos(ph), Ui = f32sin(ph);
    float Cv = Crow[i];
    ar = __fadd_rn(ar, __fmul_rn(Cv, Ur));
    ai = __fadd_rn(ai, __fmul_rn(Cv, Ui));
  }
  Cp[(size_t)(k * 64 + j) * MOUT + m] = make_float2(ar, ai);
}

// ---------------------------------------------------------------------------
__global__ void k_xc(const float* __restrict__ x, const float* __restrict__ R,
                     float* __restrict__ xcq) {
  int idx = blockIdx.x * blockDim.x + threadIdx.x;
  if (idx >= TLEN * BSZ * KP) return;
  int k = idx & 15;
  int b = (idx >> 4) & 15;
  int t = idx >> 8;
  const float4* xr = (const float4*)(x + ((size_t)b * TLEN + t) * DIN);
  double acc = 0.0;
  #pragma unroll 8
  for (int d4 = 0; d4 < DIN / 4; ++d4) {
    float4 v = xr[d4];
    acc = fma((double)v.x, (double)R[(d4 * 4 + 0) * KP + k], acc);
    acc = fma((double)v.y, (double)R[(d4 * 4 + 1) * KP + k], acc);
    acc = fma((double)v.z, (double)R[(d4 * 4 + 2) * KP + k], acc);
    acc = fma((double)v.w, (double)R[(d4 * 4 + 3) * KP + k], acc);
  }
  xcq[idx] = (float)acc;
}

// ---------------------------------------------------------------------------
// Fused two-pass scan, complex64-faithful (same ops as round 4, hoisted guard
// + explicit next-x prefetch rotation; values bit-identical).
__global__ __launch_bounds__(64) void k_scan(const float2* __restrict__ lam,
                        const float2* __restrict__ Bq,
                        const float* __restrict__ xcq,
                        float2* __restrict__ S2,
                        float* __restrict__ state, int c) {
  int j = threadIdx.x;                 // 0..63
  int chain = blockIdx.x;              // b*16 + k
  int b = chain >> 4, k = chain & 15;
  int mode = k * 64 + j;
  float lr = lam[mode].x, li = lam[mode].y;
  float Br = Bq[mode].x,  Bi = Bq[mode].y;
  float* st = state + (size_t)(chain * 64 + j) * 4;
  float s1r, s1i, s2r, s2i;
  if (c == 0) { s1r = s1i = s2r = s2i = 0.f; }
  else        { s1r = st[0]; s1i = st[1]; s2r = st[2]; s2i = st[3]; }
  int t0 = c * CHUNK_T;
  const float* xp = xcq + (size_t)b * KP + k;   // + t*256 strides
  int tlBeg = (c == 0) ? 1 : 0;
  if (c == 0)  // t = 0: store initial zeros
    S2[(size_t)(0 * BSZ + b) * 1024 + mode] = make_float2(s2r, s2i);
  float xq = xp[(size_t)(t0 + tlBeg - 1) * (BSZ * KP)];
  #pragma unroll 2
  for (int tl = tlBeg; tl < CHUNK_T; ++tl) {
    float xq_next = (tl + 1 < CHUNK_T) ? xp[(size_t)(t0 + tl) * (BSZ * KP)] : 0.f;
    float bxr = __fmul_rn(xq, Br), bxi = __fmul_rn(xq, Bi);
    float lsr = __fsub_rn(__fmul_rn(lr, s1r), __fmul_rn(li, s1i));
    float lsi = __fadd_rn(__fmul_rn(lr, s1i), __fmul_rn(li, s1r));
    float h  = (float)sqrt((double)lsr * lsr + (double)lsi * lsi);
    float h2 = __fmul_rn(h, h);
    float sm = __fadd_rn(1.0f, h2);
    float al = __fdiv_rn(1.0f, __fsqrt_rn(sm));
    float a2r = __fmul_rn(al, lr), a2i = __fmul_rn(al, li);
    float t2r = __fsub_rn(__fmul_rn(a2r, s2r), __fmul_rn(a2i, s2i));
    float t2i = __fadd_rn(__fmul_rn(a2r, s2i), __fmul_rn(a2i, s2r));
    s2r = __fadd_rn(t2r, bxr);
    s2i = __fadd_rn(t2i, bxi);
    s1r = __fadd_rn(lsr, bxr);
    s1i = __fadd_rn(lsi, bxi);
    S2[(size_t)(tl * BSZ + b) * 1024 + mode] = make_float2(s2r, s2i);
    xq = xq_next;
  }
  st[0] = s1r; st[1] = s1i; st[2] = s2r; st[3] = s2i;
}

// ---------------------------------------------------------------------------
// k_y v2: BM=32 x BN=64 tile, 256 threads (2 rows x 4 cols each), LDS 48 KB
// (3 blocks/CU). Arithmetic per output element identical to round 4:
// k ascending; inner n=0..63 ascending: acc=fadd(acc, fsub(fmul,fmul));
// yk=fadd(fadd(acc, fmul(xc,D)), Do); msum=fadd(msum,yk); out=fdiv(msum,16).
__global__ __launch_bounds__(256) void k_y(const float2* __restrict__ S2,
                     const float2* __restrict__ Cp, const float* __restrict__ xcq,
                     const float* __restrict__ D, const float* __restrict__ Dov,
                     float* __restrict__ out, int c) {
  __shared__ __align__(16) float2 sS2[32][64];   // 16 KB [row][mode]
  __shared__ __align__(16) float2 sCp[64][64];   // 32 KB [mode][col]
  int tid = threadIdx.x;
  int rowBase = (blockIdx.x >> 1) * 32;          // chunk-local row
  int colBase = (blockIdx.x & 1) * 64;
  int cg = tid & 15;                 // col group -> cols cg*4..+3
  int rg = tid >> 4;                 // row group -> rows rg*2..+1
  int c0 = cg * 4;
  int r0 = rg * 2;
  float msum[2][4] = {};
  for (int k = 0; k < KP; ++k) {
    __syncthreads();
    // stage S2 tile: 32 rows x 64 modes -> 1024 float4s? (16KB/16B=1024); 4/thread
    #pragma unroll
    for (int i = tid; i < 32 * 32; i += 256) {
      int r = i >> 5, n2 = (i & 31) * 2;
      float4 v = *(const float4*)(S2 + (size_t)(rowBase + r) * 1024 + k * 64 + n2);
      *(float4*)&sS2[r][n2] = v;
    }
    // stage Cp tile: 64 modes x 64 cols -> 2048 float4s; 8/thread
    #pragma unroll
    for (int i = tid; i < 64 * 32; i += 256) {
      int n = i >> 5, c2 = (i & 31) * 2;
      float4 v = *(const float4*)(Cp + (size_t)(k * 64 + n) * MOUT + colBase + c2);
      *(float4*)&sCp[n][c2] = v;
    }
    __syncthreads();
    float accn[2][4] = {};
    #pragma unroll 4
    for (int n = 0; n < 64; ++n) {
      float4 cpA = *(const float4*)&sCp[n][c0];      // cols c0, c0+1
      float4 cpB = *(const float4*)&sCp[n][c0 + 2];  // cols c0+2, c0+3
      float2 sA = sS2[r0][n];
      float2 sB = sS2[r0 + 1][n];
      float cx[4] = {cpA.x, cpA.z, cpB.x, cpB.z};
      float cy[4] = {cpA.y, cpA.w, cpB.y, cpB.w};
      #pragma unroll
      for (int cc = 0; cc < 4; ++cc) {
        accn[0][cc] = __fadd_rn(accn[0][cc],
            __fsub_rn(__fmul_rn(sA.x, cx[cc]), __fmul_rn(sA.y, cy[cc])));
        accn[1][cc] = __fadd_rn(accn[1][cc],
            __fsub_rn(__fmul_rn(sB.x, cx[cc]), __fmul_rn(sB.y, cy[cc])));
      }
    }
    // epilogue per k (global reads, L1-hot; order matches round 4)
    float4 dA = *(const float4*)(D + k * MOUT + colBase + c0);
    float4 oA = *(const float4*)(Dov + colBase + c0);
    float dv[4] = {dA.x, dA.y, dA.z, dA.w};
    float ov[4] = {oA.x, oA.y, oA.z, oA.w};
    float xv0 = xcq[(size_t)(c * 4096 + rowBase + r0) * KP + k];
    float xv1 = xcq[(size_t)(c * 4096 + rowBase + r0 + 1) * KP + k];
    #pragma unroll
    for (int cc = 0; cc < 4; ++cc) {
      float y0 = __fadd_rn(accn[0][cc], __fmul_rn(xv0, dv[cc]));
      float y1 = __fadd_rn(accn[1][cc], __fmul_rn(xv1, dv[cc]));
      y0 = __fadd_rn(y0, ov[cc]);
      y1 = __fadd_rn(y1, ov[cc]);
      msum[0][cc] = __fadd_rn(msum[0][cc], y0);
      msum[1][cc] = __fadd_rn(msum[1][cc], y1);
    }
  }
  #pragma unroll
  for (int rr = 0; rr < 2; ++rr) {
    int rg_glob = c * 4096 + rowBase + r0 + rr;
    int t = rg_glob >> 4, b = rg_glob & 15;
    float* op = out + ((size_t)b * TLEN + t) * MOUT + colBase + c0;
    float4 res;
    res.x = __fdiv_rn(msum[rr][0], 16.0f);
    res.y = __fdiv_rn(msum[rr][1], 16.0f);
    res.z = __fdiv_rn(msum[rr][2], 16.0f);
    res.w = __fdiv_rn(msum[rr][3], 16.0f);
    *(float4*)op = res;
  }
}

// ---------------------------------------------------------------------------
extern "C" void kernel_launch(void* const* d_in, const int* in_sizes, int n_in,
                              void* d_out, int out_size, void* d_ws, size_t ws_size,
                              hipStream_t stream) {
  const float* x     = (const float*)d_in[0];
  const float* R     = (const float*)d_in[1];
  const float* theta = (const float*)d_in[2];
  const float* C     = (const float*)d_in[3];
  const float* D     = (const float*)d_in[4];
  const float* Do    = (const float*)d_in[5];
  float* out = (float*)d_out;
  float* ws  = (float*)d_ws;
  float*  xcq = ws + XCQ_OFF;
  float2* lam = (float2*)(ws + LAM_OFF);
  float2* Bq  = (float2*)(ws + BQ_OFF);
  float2* Cp  = (float2*)(ws + CP_OFF);
  float*  st  = ws + ST_OFF;
  float2* S2  = (float2*)(ws + S2_OFF);

  hipLaunchKernelGGL(k_lam_B, dim3(4),    dim3(256), 0, stream, theta, lam, Bq);
  hipLaunchKernelGGL(k_Cp,    dim3(512),  dim3(256), 0, stream, theta, C, Cp);
  hipLaunchKernelGGL(k_xc,    dim3(1024), dim3(256), 0, stream, x, R, xcq);
  for (int c = 0; c < NCHUNK; ++c) {
    hipLaunchKernelGGL(k_scan, dim3(256), dim3(64),  0, stream, lam, Bq, xcq, S2, st, c);
    hipLaunchKernelGGL(k_y,    dim3(256), dim3(256), 0, stream, S2, Cp, xcq, D, Do, out, c);
  }
}

// Round 6
// 569.488 us; speedup vs baseline: 2.2573x; 1.2750x over previous
//
#include <hip/hip_runtime.h>
#include <math.h>

#define TLEN 1024
#define BSZ  16
#define DIN  128
#define KP   16
#define NEIG 64
#define MOUT 128
#define CHUNK_T 256
#define NCHUNK  4

// ws layout (float units) — complex64-faithful pipeline (unchanged from round 5)
static constexpr size_t XCQ_OFF = 0;        // 262144: xc quantized f32 [t][b][k]
static constexpr size_t LAM_OFF = 262144;   // 2048:  lambda c32 [k*64+j] float2
static constexpr size_t BQ_OFF  = 264192;   // 2048:  B' c32 [k*64+j] float2
static constexpr size_t CP_OFF  = 266240;   // 262144: Cp c32 [(k*64+j)*128+m] float2
static constexpr size_t ST_OFF  = 528384;   // 65536: scan state (s1,s2) c32 per mode-lane
static constexpr size_t S2_OFF  = 593920;   // 8388608: s2 chunk, 4096 rows x 1024 modes float2
// total: 8,982,528 floats = 35.9 MB

__device__ __forceinline__ float f32cos(float x) { return (float)cos((double)x); }
__device__ __forceinline__ float f32sin(float x) { return (float)sin((double)x); }

// numpy complex64 division (Smith's algorithm), all ops f32-rounded.
__device__ __forceinline__ float2 cdiv32(float ar, float ai, float cr, float ci) {
  float2 o;
  if (fabsf(ci) <= fabsf(cr)) {
    float rat = __fdiv_rn(ci, cr);
    float scl = __fdiv_rn(1.0f, __fadd_rn(cr, __fmul_rn(ci, rat)));
    o.x = __fmul_rn(__fadd_rn(ar, __fmul_rn(ai, rat)), scl);
    o.y = __fmul_rn(__fsub_rn(ai, __fmul_rn(ar, rat)), scl);
  } else {
    float rat = __fdiv_rn(cr, ci);
    float scl = __fdiv_rn(1.0f, __fadd_rn(ci, __fmul_rn(cr, rat)));
    o.x = __fmul_rn(__fadd_rn(__fmul_rn(ar, rat), ai), scl);
    o.y = __fmul_rn(__fsub_rn(__fmul_rn(ai, rat), ar), scl);
  }
  return o;
}

// ---------------------------------------------------------------------------
// v2: one wave per (k,j). 64 lanes compute the clog terms in parallel; lane 0
// performs the order-preserving sequential f32 sum (i==j contributes exact 0).
__global__ __launch_bounds__(256) void k_lam_B(const float* __restrict__ theta,
                        float2* __restrict__ lam, float2* __restrict__ Bq) {
  __shared__ float2 terms[4][64];
  int wid  = threadIdx.x >> 6;
  int lane = threadIdx.x & 63;
  int idx = blockIdx.x * 4 + wid;        // (k,j)
  int k = idx >> 6, j = idx & 63;
  float thj = (j < 32) ? theta[k * 32 + j] : -theta[k * 32 + (j - 32)];
  float ljr = f32cos(thj), lji = f32sin(thj);
  float2 tm = make_float2(0.f, 0.f);
  if (lane != j) {
    int i = lane;
    float thi = (i < 32) ? theta[k * 32 + i] : -theta[k * 32 + (i - 32)];
    float lir = f32cos(thi), lii = f32sin(thi);
    float2 r = cdiv32(lir, lii, ljr, lji);
    float tr = __fsub_rn(1.0f, r.x);
    float ti = __fsub_rn(0.0f, r.y);
    double h = sqrt((double)tr * tr + (double)ti * ti);
    tm.x = (float)log(h);
    tm.y = (float)atan2((double)ti, (double)tr);
  }
  terms[wid][lane] = tm;
  __syncthreads();
  if (lane == 0) {
    lam[idx] = make_float2(ljr, lji);
    float sr = 0.f, si = 0.f;
    for (int i = 0; i < NEIG; ++i) {       // ascending, f32-sequential
      sr = __fadd_rn(sr, terms[wid][i].x);
      si = __fadd_rn(si, terms[wid][i].y);
    }
    float er = (float)exp((double)(-sr));
    float cc = f32cos(-si), ss = f32sin(-si);
    Bq[idx] = make_float2(__fmul_rn(er, cc), __fmul_rn(er, ss));
  }
}

// ---------------------------------------------------------------------------
// v2: one block per (k,j), 128 threads (m). U[i] (m-independent) computed once
// by 64 threads; C k-slice staged in padded LDS. Same per-element op sequence.
__global__ __launch_bounds__(128) void k_Cp(const float* __restrict__ theta,
                     const float* __restrict__ C, float2* __restrict__ Cp) {
  __shared__ float2 sU[64];
  __shared__ float  sC[128][65];
  int tid = threadIdx.x;
  int kj = blockIdx.x;
  int j = kj & 63, k = kj >> 6;
  float lnim = (j < 32) ? theta[k * 32 + j] : -theta[k * 32 + (j - 32)];
  if (tid < 64) {
    int i = tid;
    float p = (float)(63 - i);
    float ph = -__fmul_rn(p, lnim);
    sU[i] = make_float2(f32cos(ph), f32sin(ph));
  }
  const float* Ck = C + ((size_t)k << 13);     // k*128*64
  for (int e = tid; e < 128 * 64; e += 128) {
    sC[e >> 6][e & 63] = Ck[e];
  }
  __syncthreads();
  int m = tid;
  float ar = 0.f, ai = 0.f;
  #pragma unroll 8
  for (int i = 0; i < NEIG; ++i) {
    float Cv = sC[m][i];
    float2 U = sU[i];
    ar = __fadd_rn(ar, __fmul_rn(Cv, U.x));
    ai = __fadd_rn(ai, __fmul_rn(Cv, U.y));
  }
  Cp[(size_t)(k * 64 + j) * MOUT + m] = make_float2(ar, ai);
}

// ---------------------------------------------------------------------------
__global__ void k_xc(const float* __restrict__ x, const float* __restrict__ R,
                     float* __restrict__ xcq) {
  int idx = blockIdx.x * blockDim.x + threadIdx.x;
  if (idx >= TLEN * BSZ * KP) return;
  int k = idx & 15;
  int b = (idx >> 4) & 15;
  int t = idx >> 8;
  const float4* xr = (const float4*)(x + ((size_t)b * TLEN + t) * DIN);
  double acc = 0.0;
  #pragma unroll 8
  for (int d4 = 0; d4 < DIN / 4; ++d4) {
    float4 v = xr[d4];
    acc = fma((double)v.x, (double)R[(d4 * 4 + 0) * KP + k], acc);
    acc = fma((double)v.y, (double)R[(d4 * 4 + 1) * KP + k], acc);
    acc = fma((double)v.z, (double)R[(d4 * 4 + 2) * KP + k], acc);
    acc = fma((double)v.w, (double)R[(d4 * 4 + 3) * KP + k], acc);
  }
  xcq[idx] = (float)acc;
}

// ---------------------------------------------------------------------------
// Scan v2: identical per-step operations, software-pipelined so the f64-sqrt
// alpha path (ls -> al) is computed at iteration END for the NEXT step; the
// recurrent chain is only cmul+cadd. Values bit-identical to round 5.
__global__ __launch_bounds__(64) void k_scan(const float2* __restrict__ lam,
                        const float2* __restrict__ Bq,
                        const float* __restrict__ xcq,
                        float2* __restrict__ S2,
                        float* __restrict__ state, int c) {
  int j = threadIdx.x;                 // 0..63
  int chain = blockIdx.x;              // b*16 + k
  int b = chain >> 4, k = chain & 15;
  int mode = k * 64 + j;
  float lr = lam[mode].x, li = lam[mode].y;
  float Br = Bq[mode].x,  Bi = Bq[mode].y;
  float* st = state + (size_t)(chain * 64 + j) * 4;
  float s1r, s1i, s2r, s2i;
  if (c == 0) { s1r = s1i = s2r = s2i = 0.f; }
  else        { s1r = st[0]; s1i = st[1]; s2r = st[2]; s2i = st[3]; }
  // pipeline prologue: ls = lam*s1 ; al = alpha(ls)   (same ops as in-loop)
  float lsr = __fsub_rn(__fmul_rn(lr, s1r), __fmul_rn(li, s1i));
  float lsi = __fadd_rn(__fmul_rn(lr, s1i), __fmul_rn(li, s1r));
  float h  = (float)sqrt((double)lsr * lsr + (double)lsi * lsi);
  float al = __fdiv_rn(1.0f, __fsqrt_rn(__fadd_rn(1.0f, __fmul_rn(h, h))));
  int t0 = c * CHUNK_T;
  const float* xp = xcq + (size_t)b * KP + k;
  int tlBeg = (c == 0) ? 1 : 0;
  if (c == 0)
    S2[(size_t)(0 * BSZ + b) * 1024 + mode] = make_float2(s2r, s2i);
  float xq = xp[(size_t)(t0 + tlBeg - 1) * (BSZ * KP)];
  #pragma unroll 4
  for (int tl = tlBeg; tl < CHUNK_T; ++tl) {
    float xq_next = (tl + 1 < CHUNK_T) ? xp[(size_t)(t0 + tl) * (BSZ * KP)] : 0.f;
    float bxr = __fmul_rn(xq, Br), bxi = __fmul_rn(xq, Bi);
    float a2r = __fmul_rn(al, lr), a2i = __fmul_rn(al, li);
    float t2r = __fsub_rn(__fmul_rn(a2r, s2r), __fmul_rn(a2i, s2i));
    float t2i = __fadd_rn(__fmul_rn(a2r, s2i), __fmul_rn(a2i, s2r));
    s2r = __fadd_rn(t2r, bxr);
    s2i = __fadd_rn(t2i, bxi);
    s1r = __fadd_rn(lsr, bxr);          // s1[t] = ls + bx
    s1i = __fadd_rn(lsi, bxi);
    // next-step ls and alpha (off the recurrent critical path)
    lsr = __fsub_rn(__fmul_rn(lr, s1r), __fmul_rn(li, s1i));
    lsi = __fadd_rn(__fmul_rn(lr, s1i), __fmul_rn(li, s1r));
    h  = (float)sqrt((double)lsr * lsr + (double)lsi * lsi);
    al = __fdiv_rn(1.0f, __fsqrt_rn(__fadd_rn(1.0f, __fmul_rn(h, h))));
    S2[(size_t)(tl * BSZ + b) * 1024 + mode] = make_float2(s2r, s2i);
    xq = xq_next;
  }
  st[0] = s1r; st[1] = s1i; st[2] = s2r; st[3] = s2i;
}

// ---------------------------------------------------------------------------
// k_y v3: BM=32 x BN=64, 256 threads, r=2 x c=4 microtile. LDS transposed +
// padded: sS2t[mode][row] (2-way free), sCp[mode][col] with cg=tid>>4 giving
// 4 broadcast address-groups per wave (conflict-free). Per-element arithmetic
// identical to rounds 4/5.
__global__ __launch_bounds__(256) void k_y(const float2* __restrict__ S2,
                     const float2* __restrict__ Cp, const float* __restrict__ xcq,
                     const float* __restrict__ D, const float* __restrict__ Dov,
                     float* __restrict__ out, int c) {
  __shared__ __align__(16) float2 sS2t[64][34];  // [mode][row], pad 2 -> 17.4 KB
  __shared__ __align__(16) float2 sCp[64][66];   // [mode][col], pad 2 -> 33.8 KB
  int tid = threadIdx.x;
  int rowBase = (blockIdx.x >> 1) * 32;          // chunk-local row
  int colBase = (blockIdx.x & 1) * 64;
  int rg = tid & 15;                 // row group -> rows rg*2..+1
  int cg = tid >> 4;                 // col group -> cols cg*4..+3 (4/wave, bcast)
  int r0 = rg * 2;
  int c0 = cg * 4;
  float msum[2][4] = {};
  for (int k = 0; k < KP; ++k) {
    __syncthreads();
    // stage S2 tile transposed: [n][r]; global reads coalesced over modes
    #pragma unroll
    for (int it = 0; it < 4; ++it) {
      int r  = (tid >> 5) + it * 8;
      int n2 = (tid & 31) * 2;
      float4 v = *(const float4*)(S2 + (size_t)(rowBase + r) * 1024 + k * 64 + n2);
      sS2t[n2][r]     = make_float2(v.x, v.y);
      sS2t[n2 + 1][r] = make_float2(v.z, v.w);
    }
    // stage Cp tile: [n][col]; global reads coalesced over cols
    #pragma unroll
    for (int it = 0; it < 4; ++it) {
      int n  = (tid >> 4) + it * 16;
      int c2 = (tid & 15) * 4;
      const float2* gp = Cp + (size_t)(k * 64 + n) * MOUT + colBase + c2;
      float4 g0 = *(const float4*)gp;
      float4 g1 = *(const float4*)(gp + 2);
      *(float4*)&sCp[n][c2]     = g0;
      *(float4*)&sCp[n][c2 + 2] = g1;
    }
    __syncthreads();
    float accn[2][4] = {};
    #pragma unroll 4
    for (int n = 0; n < 64; ++n) {
      float4 s4  = *(const float4*)&sS2t[n][r0];      // rows r0, r0+1
      float4 cpA = *(const float4*)&sCp[n][c0];       // cols c0, c0+1
      float4 cpB = *(const float4*)&sCp[n][c0 + 2];   // cols c0+2, c0+3
      float cx[4] = {cpA.x, cpA.z, cpB.x, cpB.z};
      float cy[4] = {cpA.y, cpA.w, cpB.y, cpB.w};
      #pragma unroll
      for (int cc = 0; cc < 4; ++cc) {
        accn[0][cc] = __fadd_rn(accn[0][cc],
            __fsub_rn(__fmul_rn(s4.x, cx[cc]), __fmul_rn(s4.y, cy[cc])));
        accn[1][cc] = __fadd_rn(accn[1][cc],
            __fsub_rn(__fmul_rn(s4.z, cx[cc]), __fmul_rn(s4.w, cy[cc])));
      }
    }
    // epilogue per k (global reads, L1-hot; order matches rounds 4/5)
    float4 dA = *(const float4*)(D + k * MOUT + colBase + c0);
    float4 oA = *(const float4*)(Dov + colBase + c0);
    float dv[4] = {dA.x, dA.y, dA.z, dA.w};
    float ov[4] = {oA.x, oA.y, oA.z, oA.w};
    float xv0 = xcq[(size_t)(c * 4096 + rowBase + r0) * KP + k];
    float xv1 = xcq[(size_t)(c * 4096 + rowBase + r0 + 1) * KP + k];
    #pragma unroll
    for (int cc = 0; cc < 4; ++cc) {
      float y0 = __fadd_rn(accn[0][cc], __fmul_rn(xv0, dv[cc]));
      float y1 = __fadd_rn(accn[1][cc], __fmul_rn(xv1, dv[cc]));
      y0 = __fadd_rn(y0, ov[cc]);
      y1 = __fadd_rn(y1, ov[cc]);
      msum[0][cc] = __fadd_rn(msum[0][cc], y0);
      msum[1][cc] = __fadd_rn(msum[1][cc], y1);
    }
  }
  #pragma unroll
  for (int rr = 0; rr < 2; ++rr) {
    int rg_glob = c * 4096 + rowBase + r0 + rr;
    int t = rg_glob >> 4, b = rg_glob & 15;
    float* op = out + ((size_t)b * TLEN + t) * MOUT + colBase + c0;
    float4 res;
    res.x = __fdiv_rn(msum[rr][0], 16.0f);
    res.y = __fdiv_rn(msum[rr][1], 16.0f);
    res.z = __fdiv_rn(msum[rr][2], 16.0f);
    res.w = __fdiv_rn(msum[rr][3], 16.0f);
    *(float4*)op = res;
  }
}

// ---------------------------------------------------------------------------
extern "C" void kernel_launch(void* const* d_in, const int* in_sizes, int n_in,
                              void* d_out, int out_size, void* d_ws, size_t ws_size,
                              hipStream_t stream) {
  const float* x     = (const float*)d_in[0];
  const float* R     = (const float*)d_in[1];
  const float* theta = (const float*)d_in[2];
  const float* C     = (const float*)d_in[3];
  const float* D     = (const float*)d_in[4];
  const float* Do    = (const float*)d_in[5];
  float* out = (float*)d_out;
  float* ws  = (float*)d_ws;
  float*  xcq = ws + XCQ_OFF;
  float2* lam = (float2*)(ws + LAM_OFF);
  float2* Bq  = (float2*)(ws + BQ_OFF);
  float2* Cp  = (float2*)(ws + CP_OFF);
  float*  st  = ws + ST_OFF;
  float2* S2  = (float2*)(ws + S2_OFF);

  hipLaunchKernelGGL(k_lam_B, dim3(256),  dim3(256), 0, stream, theta, lam, Bq);
  hipLaunchKernelGGL(k_Cp,    dim3(1024), dim3(128), 0, stream, theta, C, Cp);
  hipLaunchKernelGGL(k_xc,    dim3(1024), dim3(256), 0, stream, x, R, xcq);
  for (int c = 0; c < NCHUNK; ++c) {
    hipLaunchKernelGGL(k_scan, dim3(256), dim3(64),  0, stream, lam, Bq, xcq, S2, st, c);
    hipLaunchKernelGGL(k_y,    dim3(256), dim3(256), 0, stream, S2, Cp, xcq, D, Do, out, c);
  }
}

// Round 7
// 408.290 us; speedup vs baseline: 3.1486x; 1.3948x over previous
//
#include <hip/hip_runtime.h>
#include <math.h>

#define TLEN 1024
#define BSZ  16
#define DIN  128
#define KP   16
#define NEIG 64
#define MOUT 128
#define CHUNK_T 256
#define NCHUNK  4

// ws layout (float units)
static constexpr size_t XCQ_OFF = 0;        // 262144: xc f32 [t][b][k]
static constexpr size_t LAM_OFF = 262144;   // 2048:  lambda c32
static constexpr size_t BQ_OFF  = 264192;   // 2048:  B' c32
static constexpr size_t CP_OFF  = 266240;   // 262144: Cp c32 [(k*64+j)*128+m]
static constexpr size_t ST_OFF  = 528384;   // 65536: scan state
static constexpr size_t S2_OFF  = 593920;   // 8388608: s2 chunk [4096][1024] float2
static constexpr size_t P_OFF   = 8982528;  // 1048576: k-split partials [2][4096][128]
// total: 10,031,104 floats = 40.1 MB (ws >= 69.7 MB proven in rounds 1-2)

__device__ __forceinline__ float f32cos(float x) { return (float)cos((double)x); }
__device__ __forceinline__ float f32sin(float x) { return (float)sin((double)x); }

__device__ __forceinline__ float2 cdiv32(float ar, float ai, float cr, float ci) {
  float2 o;
  if (fabsf(ci) <= fabsf(cr)) {
    float rat = __fdiv_rn(ci, cr);
    float scl = __fdiv_rn(1.0f, __fadd_rn(cr, __fmul_rn(ci, rat)));
    o.x = __fmul_rn(__fadd_rn(ar, __fmul_rn(ai, rat)), scl);
    o.y = __fmul_rn(__fsub_rn(ai, __fmul_rn(ar, rat)), scl);
  } else {
    float rat = __fdiv_rn(cr, ci);
    float scl = __fdiv_rn(1.0f, __fadd_rn(ci, __fmul_rn(cr, rat)));
    o.x = __fmul_rn(__fadd_rn(__fmul_rn(ar, rat), ai), scl);
    o.y = __fmul_rn(__fsub_rn(__fmul_rn(ai, rat), ar), scl);
  }
  return o;
}

// ---------------------------------------------------------------------------
__global__ __launch_bounds__(256) void k_lam_B(const float* __restrict__ theta,
                        float2* __restrict__ lam, float2* __restrict__ Bq) {
  __shared__ float2 terms[4][64];
  int wid  = threadIdx.x >> 6;
  int lane = threadIdx.x & 63;
  int idx = blockIdx.x * 4 + wid;
  int k = idx >> 6, j = idx & 63;
  float thj = (j < 32) ? theta[k * 32 + j] : -theta[k * 32 + (j - 32)];
  float ljr = f32cos(thj), lji = f32sin(thj);
  float2 tm = make_float2(0.f, 0.f);
  if (lane != j) {
    int i = lane;
    float thi = (i < 32) ? theta[k * 32 + i] : -theta[k * 32 + (i - 32)];
    float lir = f32cos(thi), lii = f32sin(thi);
    float2 r = cdiv32(lir, lii, ljr, lji);
    float tr = __fsub_rn(1.0f, r.x);
    float ti = __fsub_rn(0.0f, r.y);
    double h = sqrt((double)tr * tr + (double)ti * ti);
    tm.x = (float)log(h);
    tm.y = (float)atan2((double)ti, (double)tr);
  }
  terms[wid][lane] = tm;
  __syncthreads();
  if (lane == 0) {
    lam[idx] = make_float2(ljr, lji);
    float sr = 0.f, si = 0.f;
    for (int i = 0; i < NEIG; ++i) {
      sr = __fadd_rn(sr, terms[wid][i].x);
      si = __fadd_rn(si, terms[wid][i].y);
    }
    float er = (float)exp((double)(-sr));
    float cc = f32cos(-si), ss = f32sin(-si);
    Bq[idx] = make_float2(__fmul_rn(er, cc), __fmul_rn(er, ss));
  }
}

// ---------------------------------------------------------------------------
__global__ __launch_bounds__(128) void k_Cp(const float* __restrict__ theta,
                     const float* __restrict__ C, float2* __restrict__ Cp) {
  __shared__ float2 sU[64];
  __shared__ float  sC[128][65];
  int tid = threadIdx.x;
  int kj = blockIdx.x;
  int j = kj & 63, k = kj >> 6;
  float lnim = (j < 32) ? theta[k * 32 + j] : -theta[k * 32 + (j - 32)];
  if (tid < 64) {
    int i = tid;
    float p = (float)(63 - i);
    float ph = -__fmul_rn(p, lnim);
    sU[i] = make_float2(f32cos(ph), f32sin(ph));
  }
  const float* Ck = C + ((size_t)k << 13);
  for (int e = tid; e < 128 * 64; e += 128) {
    sC[e >> 6][e & 63] = Ck[e];
  }
  __syncthreads();
  int m = tid;
  float ar = 0.f, ai = 0.f;
  #pragma unroll 8
  for (int i = 0; i < NEIG; ++i) {
    float Cv = sC[m][i];
    float2 U = sU[i];
    ar = __fadd_rn(ar, __fmul_rn(Cv, U.x));
    ai = __fadd_rn(ai, __fmul_rn(Cv, U.y));
  }
  Cp[(size_t)(k * 64 + j) * MOUT + m] = make_float2(ar, ai);
}

// ---------------------------------------------------------------------------
__global__ void k_xc(const float* __restrict__ x, const float* __restrict__ R,
                     float* __restrict__ xcq) {
  int idx = blockIdx.x * blockDim.x + threadIdx.x;
  if (idx >= TLEN * BSZ * KP) return;
  int k = idx & 15;
  int b = (idx >> 4) & 15;
  int t = idx >> 8;
  const float4* xr = (const float4*)(x + ((size_t)b * TLEN + t) * DIN);
  double acc = 0.0;
  #pragma unroll 8
  for (int d4 = 0; d4 < DIN / 4; ++d4) {
    float4 v = xr[d4];
    acc = fma((double)v.x, (double)R[(d4 * 4 + 0) * KP + k], acc);
    acc = fma((double)v.y, (double)R[(d4 * 4 + 1) * KP + k], acc);
    acc = fma((double)v.z, (double)R[(d4 * 4 + 2) * KP + k], acc);
    acc = fma((double)v.w, (double)R[(d4 * 4 + 3) * KP + k], acc);
  }
  xcq[idx] = (float)acc;
}

// ---------------------------------------------------------------------------
// Scan v3: arithmetic bit-identical to round 6; xq window staged in LDS once
// (removes the per-step dependent global load from the recurrence).
__global__ __launch_bounds__(64) void k_scan(const float2* __restrict__ lam,
                        const float2* __restrict__ Bq,
                        const float* __restrict__ xcq,
                        float2* __restrict__ S2,
                        float* __restrict__ state, int c) {
  __shared__ float sXq[CHUNK_T];
  int j = threadIdx.x;                 // 0..63
  int chain = blockIdx.x;              // b*16 + k
  int b = chain >> 4, k = chain & 15;
  int mode = k * 64 + j;
  int t0 = c * CHUNK_T;
  int tlBeg = (c == 0) ? 1 : 0;
  // stage xq window: value used at step tl is xcq[t0+tl-1] = sXq[tl - tlBeg]
  for (int i = j; i < CHUNK_T; i += 64) {
    int g = t0 + tlBeg - 1 + i;        // always in [0, 1023]
    sXq[i] = xcq[(size_t)g * (BSZ * KP) + b * KP + k];
  }
  __syncthreads();
  float lr = lam[mode].x, li = lam[mode].y;
  float Br = Bq[mode].x,  Bi = Bq[mode].y;
  float* st = state + (size_t)(chain * 64 + j) * 4;
  float s1r, s1i, s2r, s2i;
  if (c == 0) { s1r = s1i = s2r = s2i = 0.f; }
  else        { s1r = st[0]; s1i = st[1]; s2r = st[2]; s2i = st[3]; }
  // pipeline prologue: ls = lam*s1 ; al = alpha(ls)
  float lsr = __fsub_rn(__fmul_rn(lr, s1r), __fmul_rn(li, s1i));
  float lsi = __fadd_rn(__fmul_rn(lr, s1i), __fmul_rn(li, s1r));
  float h  = (float)sqrt((double)lsr * lsr + (double)lsi * lsi);
  float al = __fdiv_rn(1.0f, __fsqrt_rn(__fadd_rn(1.0f, __fmul_rn(h, h))));
  if (c == 0)
    S2[(size_t)(0 * BSZ + b) * 1024 + mode] = make_float2(s2r, s2i);
  #pragma unroll 4
  for (int tl = tlBeg; tl < CHUNK_T; ++tl) {
    float xq = sXq[tl - tlBeg];
    float bxr = __fmul_rn(xq, Br), bxi = __fmul_rn(xq, Bi);
    float a2r = __fmul_rn(al, lr), a2i = __fmul_rn(al, li);
    float t2r = __fsub_rn(__fmul_rn(a2r, s2r), __fmul_rn(a2i, s2i));
    float t2i = __fadd_rn(__fmul_rn(a2r, s2i), __fmul_rn(a2i, s2r));
    s2r = __fadd_rn(t2r, bxr);
    s2i = __fadd_rn(t2i, bxi);
    s1r = __fadd_rn(lsr, bxr);
    s1i = __fadd_rn(lsi, bxi);
    lsr = __fsub_rn(__fmul_rn(lr, s1r), __fmul_rn(li, s1i));
    lsi = __fadd_rn(__fmul_rn(lr, s1i), __fmul_rn(li, s1r));
    h  = (float)sqrt((double)lsr * lsr + (double)lsi * lsi);
    al = __fdiv_rn(1.0f, __fsqrt_rn(__fadd_rn(1.0f, __fmul_rn(h, h))));
    S2[(size_t)(tl * BSZ + b) * 1024 + mode] = make_float2(s2r, s2i);
  }
  st[0] = s1r; st[1] = s1i; st[2] = s2r; st[3] = s2i;
}

// ---------------------------------------------------------------------------
// k_y v5: split-k x2 -> 512 blocks (2/CU). BM=32 x BN=64, 256 threads,
// 2 rows (rg, rg+16) x 4 cols per thread. Partial msum over k in [kh*8, kh*8+8)
// written WITHOUT /16 to P[kh]. n-sum and within-half k-sum keep the exact
// sequential f32 order of rounds 4-6.
__global__ __launch_bounds__(256) void k_y(const float2* __restrict__ S2,
                     const float2* __restrict__ Cp, const float* __restrict__ xcq,
                     const float* __restrict__ D, const float* __restrict__ Dov,
                     float* __restrict__ P, int c) {
  __shared__ __align__(16) float2 sS2[32][66];   // [row][mode], 16.9 KB
  __shared__ __align__(16) float2 sCp[64][66];   // [mode][col], 33.8 KB
  int tid = threadIdx.x;
  int bid = blockIdx.x;
  int kh   = bid >> 8;                 // 0/1: k half
  int tile = bid & 255;
  int rowBase = (tile >> 1) * 32;      // chunk-local row
  int colBase = (tile & 1) * 64;
  int rg = tid & 15;                   // rows rg, rg+16
  int cg = tid >> 4;                   // cols cg*4 .. +3
  int c0 = cg * 4;
  float msum[2][4] = {};
  int kbeg = kh * 8;
  for (int kk = 0; kk < 8; ++kk) {
    int k = kbeg + kk;
    __syncthreads();
    // stage S2 tile [32][64] float2: 1024 float4s, 4/thread
    #pragma unroll
    for (int it = 0; it < 4; ++it) {
      int e = tid + it * 256;
      int r = e >> 5, q = e & 31;
      float4 v = *(const float4*)(S2 + (size_t)(rowBase + r) * 1024 + k * 64 + q * 2);
      *(float4*)&sS2[r][q * 2] = v;
    }
    // stage Cp tile [64][64] float2: 2048 float4s, 8/thread
    #pragma unroll
    for (int it = 0; it < 8; ++it) {
      int e = tid + it * 256;
      int n = e >> 5, q = e & 31;
      float4 v = *(const float4*)(Cp + (size_t)(k * 64 + n) * MOUT + colBase + q * 2);
      *(float4*)&sCp[n][q * 2] = v;
    }
    __syncthreads();
    float accn[2][4] = {};
    #pragma unroll 4
    for (int n = 0; n < 64; ++n) {
      float2 sA = sS2[rg][n];
      float2 sB = sS2[rg + 16][n];
      float4 cpA = *(const float4*)&sCp[n][c0];      // cols c0, c0+1
      float4 cpB = *(const float4*)&sCp[n][c0 + 2];  // cols c0+2, c0+3
      float cx[4] = {cpA.x, cpA.z, cpB.x, cpB.z};
      float cy[4] = {cpA.y, cpA.w, cpB.y, cpB.w};
      #pragma unroll
      for (int cc = 0; cc < 4; ++cc) {
        accn[0][cc] = __fadd_rn(accn[0][cc],
            __fsub_rn(__fmul_rn(sA.x, cx[cc]), __fmul_rn(sA.y, cy[cc])));
        accn[1][cc] = __fadd_rn(accn[1][cc],
            __fsub_rn(__fmul_rn(sB.x, cx[cc]), __fmul_rn(sB.y, cy[cc])));
      }
    }
    // epilogue per k (order matches rounds 4-6)
    float4 dA = *(const float4*)(D + k * MOUT + colBase + c0);
    float4 oA = *(const float4*)(Dov + colBase + c0);
    float dv[4] = {dA.x, dA.y, dA.z, dA.w};
    float ov[4] = {oA.x, oA.y, oA.z, oA.w};
    float xv0 = xcq[(size_t)(c * 4096 + rowBase + rg) * KP + k];
    float xv1 = xcq[(size_t)(c * 4096 + rowBase + rg + 16) * KP + k];
    #pragma unroll
    for (int cc = 0; cc < 4; ++cc) {
      float y0 = __fadd_rn(accn[0][cc], __fmul_rn(xv0, dv[cc]));
      float y1 = __fadd_rn(accn[1][cc], __fmul_rn(xv1, dv[cc]));
      y0 = __fadd_rn(y0, ov[cc]);
      y1 = __fadd_rn(y1, ov[cc]);
      msum[0][cc] = __fadd_rn(msum[0][cc], y0);
      msum[1][cc] = __fadd_rn(msum[1][cc], y1);
    }
  }
  #pragma unroll
  for (int rr = 0; rr < 2; ++rr) {
    int r = rowBase + rg + rr * 16;
    float* pp = P + ((size_t)kh * 4096 + r) * MOUT + colBase + c0;
    *(float4*)pp = make_float4(msum[rr][0], msum[rr][1], msum[rr][2], msum[rr][3]);
  }
}

// ---------------------------------------------------------------------------
// out = (P0 + P1) / 16, scattered to [b][t][m] layout.
__global__ __launch_bounds__(256) void k_combine(const float* __restrict__ P,
                     float* __restrict__ out, int c) {
  int idx = blockIdx.x * 256 + threadIdx.x;   // 131072 float4s
  int r  = idx >> 5;
  int m4 = (idx & 31) * 4;
  float4 p0 = *(const float4*)(P + (size_t)r * MOUT + m4);
  float4 p1 = *(const float4*)(P + ((size_t)4096 + r) * MOUT + m4);
  int rg = c * 4096 + r;
  int t = rg >> 4, b = rg & 15;
  float4 res;
  res.x = __fdiv_rn(__fadd_rn(p0.x, p1.x), 16.0f);
  res.y = __fdiv_rn(__fadd_rn(p0.y, p1.y), 16.0f);
  res.z = __fdiv_rn(__fadd_rn(p0.z, p1.z), 16.0f);
  res.w = __fdiv_rn(__fadd_rn(p0.w, p1.w), 16.0f);
  *(float4*)(out + ((size_t)b * TLEN + t) * MOUT + m4) = res;
}

// ---------------------------------------------------------------------------
extern "C" void kernel_launch(void* const* d_in, const int* in_sizes, int n_in,
                              void* d_out, int out_size, void* d_ws, size_t ws_size,
                              hipStream_t stream) {
  const float* x     = (const float*)d_in[0];
  const float* R     = (const float*)d_in[1];
  const float* theta = (const float*)d_in[2];
  const float* C     = (const float*)d_in[3];
  const float* D     = (const float*)d_in[4];
  const float* Do    = (const float*)d_in[5];
  float* out = (float*)d_out;
  float* ws  = (float*)d_ws;
  float*  xcq = ws + XCQ_OFF;
  float2* lam = (float2*)(ws + LAM_OFF);
  float2* Bq  = (float2*)(ws + BQ_OFF);
  float2* Cp  = (float2*)(ws + CP_OFF);
  float*  st  = ws + ST_OFF;
  float2* S2  = (float2*)(ws + S2_OFF);
  float*  P   = ws + P_OFF;

  hipLaunchKernelGGL(k_lam_B, dim3(256),  dim3(256), 0, stream, theta, lam, Bq);
  hipLaunchKernelGGL(k_Cp,    dim3(1024), dim3(128), 0, stream, theta, C, Cp);
  hipLaunchKernelGGL(k_xc,    dim3(1024), dim3(256), 0, stream, x, R, xcq);
  for (int c = 0; c < NCHUNK; ++c) {
    hipLaunchKernelGGL(k_scan,    dim3(256), dim3(64),  0, stream, lam, Bq, xcq, S2, st, c);
    hipLaunchKernelGGL(k_y,       dim3(512), dim3(256), 0, stream, S2, Cp, xcq, D, Do, P, c);
    hipLaunchKernelGGL(k_combine, dim3(512), dim3(256), 0, stream, P, out, c);
  }
}